// Round 5
// baseline (777.617 us; speedup 1.0000x reference)
//
#include <hip/hip_runtime.h>
#include <hip/hip_bf16.h>
#include <cstdint>
#include <cstddef>

// Problem constants
#define TT  512
#define BB  256
#define DIN 512
#define HH  128
#define NG  512   // 4*H

typedef __bf16 bf16x8 __attribute__((ext_vector_type(8)));
typedef float  f32x4  __attribute__((ext_vector_type(4)));

// ---- nonlinearities: 1 exp2 + 1 rcp each, branch-free --------------------
__device__ __forceinline__ float fast_sig(float x) {
  float e = __builtin_amdgcn_exp2f(-1.44269504f * x);
  return __builtin_amdgcn_rcpf(1.f + e);
}
__device__ __forceinline__ float fast_tanh(float x) {
  float e = __builtin_amdgcn_exp2f(-2.88539008f * x);
  return __builtin_fmaf(2.f, __builtin_amdgcn_rcpf(1.f + e), -1.f);
}

// LDS-visibility-only barrier: vmcnt (global loads/stores) stays in flight.
__device__ __forceinline__ void lgkm_barrier() {
  asm volatile("s_waitcnt lgkmcnt(0)\n\ts_barrier" ::: "memory");
}

// Agent-scope accessors for the producer->consumer handoff.
// Data is written with NORMAL stores (L2 write-combines them into full
// lines); the producer's RELEASE fetch_add emits vmcnt(0)+buffer_wbl2,
// pushing its dirty L2 lines to L3 (the coherence point) before the flag
// lands. Consumers read Xg/flags with agent-scope (sc1) loads that bypass
// their possibly-stale local L2.
__device__ __forceinline__ int ld_flag(const int* p) {
  return __hip_atomic_load(p, __ATOMIC_RELAXED, __HIP_MEMORY_SCOPE_AGENT);
}
__device__ __forceinline__ uint2 ld_xg8(const __bf16* p) {
  unsigned long long v = __hip_atomic_load((const unsigned long long*)p,
                                           __ATOMIC_RELAXED, __HIP_MEMORY_SCOPE_AGENT);
  union { unsigned long long u; uint2 v2; } cv; cv.u = v;
  return cv.v2;
}

// flags padded to one 64B line per timestep (16 ints): 512 consumer waves
// polling t+2..t+5 never contend with the producer's RMW on flags[t].
#define FLAG(t) ((t) * 16)

// ---------------- P0: weight transpose + fp32->bf16 convert + flag reset ---
__global__ void wconv_kernel(const float* __restrict__ Wi, const float* __restrict__ Wh,
                             __bf16* __restrict__ WiT, __bf16* __restrict__ WhT,
                             int* __restrict__ flags) {
  int idx = blockIdx.x * 256 + threadIdx.x;
  if (idx < TT * 16) flags[idx] = 0;           // 512 lines x 16 ints
  if (idx < DIN * NG) {
    int n = idx >> 9, k = idx & 511;
    WiT[(size_t)n * DIN + k] = (__bf16)Wi[(size_t)k * NG + n];
  }
  if (idx < HH * NG) {
    int n = idx >> 7, k = idx & 127;
    WhT[(size_t)n * HH + k] = (__bf16)Wh[(size_t)k * NG + n];
  }
}

// ---------------- gemm body: Xg = obs @ Wi + b (persistent producer) -------
// R4's LDS-staged, distance-2-prefetch main loop. NEW epilogue: instead of
// 128 scattered 2B stores per lane (15-25us of store-path occupancy per
// tile), stage each mt-pair's C-subtile through a 32KB LDS transpose buffer
// (consumer layout), then stream it out as fully-coalesced 16B/lane NORMAL
// stores (the tile's 128KB Xg region is contiguous; L2 write-combines).
// eld aliases Alds: main-loop Alds reads are drained before the first
// epilogue __syncthreads completes.
__device__ __forceinline__ void gemm_body(
    const float* __restrict__ obs, const __bf16* __restrict__ WiT,
    const float* __restrict__ bias, __bf16* __restrict__ Xg,
    int* __restrict__ flags, int p, __bf16* smem_) {
  __bf16 (*Alds)[40] = (__bf16 (*)[40])smem_;   // 10240 B (main loop)
  __bf16* eld = smem_;                          // 32768 B (epilogue, aliased)
  const int tid  = threadIdx.x;
  const int wave = tid >> 6, lane = tid & 63;
  const int l15  = lane & 15, q = lane >> 4;
  const int am = tid >> 2, aq = tid & 3;
  const int g_out = wave >> 1;                  // epilogue gate index

  const __bf16* bptr[4];
  float bbv[4];
#pragma unroll
  for (int nt = 0; nt < 4; nt++) {
    bptr[nt] = WiT + (size_t)(wave * 64 + nt * 16 + l15) * DIN + q * 8;
    bbv[nt]  = bias[wave * 64 + nt * 16 + l15];
  }

  for (int bid = p; bid < 2 * TT; bid += 192) {
    const size_t m0 = (size_t)bid * 128;

    const f32x4 fzero = {0.f, 0.f, 0.f, 0.f};
    f32x4 acc[8][4];
#pragma unroll
    for (int i = 0; i < 8; i++)
#pragma unroll
      for (int jj = 0; jj < 4; jj++) acc[i][jj] = fzero;

    const float* aptr = obs + (m0 + am) * DIN + aq * 8;

    // distance-2 slots
    float4 a0[2], a1[2];
    bf16x8 bs[2][4];
    a0[0] = *(const float4*)(aptr);      a1[0] = *(const float4*)(aptr + 4);
    a0[1] = *(const float4*)(aptr + 32); a1[1] = *(const float4*)(aptr + 36);
#pragma unroll
    for (int nt = 0; nt < 4; nt++) {
      bs[0][nt] = *(const bf16x8*)(bptr[nt]);
      bs[1][nt] = *(const bf16x8*)(bptr[nt] + 32);
    }

#pragma unroll
    for (int kc = 0; kc < DIN; kc += 32) {
      const int sl = (kc >> 5) & 1;
      if (kc) lgkm_barrier();            // prev frag reads drained
      { // stage A tile (consumes A slot sl)
        float4 f0 = a0[sl], f1 = a1[sl];
        bf16x8 v = {(__bf16)f0.x, (__bf16)f0.y, (__bf16)f0.z, (__bf16)f0.w,
                    (__bf16)f1.x, (__bf16)f1.y, (__bf16)f1.z, (__bf16)f1.w};
        *(bf16x8*)&Alds[am][aq * 8] = v;
      }
      lgkm_barrier();                    // A visible; vmcnt untouched
      int kp = kc + 64; if (kp > DIN - 32) kp = DIN - 32;   // clamped tail (unused)
      a0[sl] = *(const float4*)(aptr + kp);
      a1[sl] = *(const float4*)(aptr + kp + 4);
#pragma unroll
      for (int mt = 0; mt < 8; mt++) {
        bf16x8 af = *(const bf16x8*)&Alds[mt * 16 + l15][q * 8];
#pragma unroll
        for (int nt = 0; nt < 4; nt++)
          acc[mt][nt] = __builtin_amdgcn_mfma_f32_16x16x32_bf16(af, bs[sl][nt], acc[mt][nt], 0, 0, 0);
      }
#pragma unroll
      for (int nt = 0; nt < 4; nt++)     // refill B slot for kc+64
        bs[sl][nt] = *(const bf16x8*)(bptr[nt] + kp);
    }

    // ---- epilogue: LDS-transpose to consumer layout, coalesced stores ----
    // C row = mt*16 + q*4 + r; b = half*128 + row -> bg = half*8+mt, r0 = r.
    // Consumer layout within a tile: [mt][r][jj][q][g], jj=(wave&1)*64+nt*16
    // +l15, g=wave>>1. Two mt's (32KB) staged per pass, 4 passes.
    const int t = bid >> 1;
    const int half = bid & 1;
#pragma unroll 1
    for (int mtp = 0; mtp < 4; mtp++) {
      __syncthreads();                   // buffer free (Alds or prev pass)
#pragma unroll
      for (int mh = 0; mh < 2; mh++) {
        const int mt = mtp * 2 + mh;
#pragma unroll
        for (int nt = 0; nt < 4; nt++) {
          const int jj = (wave & 1) * 64 + nt * 16 + l15;
          const float bb = bbv[nt];
#pragma unroll
          for (int r = 0; r < 4; r++)
            eld[mh * 8192 + r * 2048 + jj * 16 + q * 4 + g_out] =
                (__bf16)(acc[mt][nt][r] + bb);
        }
      }
      __syncthreads();                   // staged
      __bf16* dst = Xg + (size_t)(t * 16 + half * 8 + mtp * 2) * 8192;
#pragma unroll
      for (int u = 0; u < 4; u++)        // 32KB = 4 x (512 thr x 16B), coalesced
        *(uint4*)(dst + u * 4096 + tid * 8) =
            *(const uint4*)(eld + u * 4096 + tid * 8);
    }

    // all waves' stores are at L2 (syncthreads drains each wave's vmcnt)
    // before wave 0's release-add walks wbl2 and publishes the flag.
    __syncthreads();
    if (tid == 0)
      __hip_atomic_fetch_add(flags + FLAG(t), 1, __ATOMIC_RELEASE, __HIP_MEMORY_SCOPE_AGENT);
  }
}

// ---------------- scan body (consumer) -------------------------------------
template<int R0>
__device__ __forceinline__ void scan_body(
    const __bf16* __restrict__ Xg, const __bf16* __restrict__ WhT,
    const int* __restrict__ done, const float* __restrict__ c0,
    const float* __restrict__ h0, float* __restrict__ out,
    const int* __restrict__ flags,
    int bg, __bf16 (*hlds)[16][HH + 8]) {
  const int tid  = threadIdx.x;
  const int wave = tid >> 6, lane = tid & 63;
  const int l15  = lane & 15, q = lane >> 4;
  const int b0 = bg * 16;
  const int j  = wave * 16 + l15;
  const int b  = b0 + q * 4 + R0;        // owned batch row
  const int row = q * 4 + R0;            // LDS row for owned batch

  // Wh B-fragments resident in registers (64 VGPR/lane)
  bf16x8 bfrag[4][4];
#pragma unroll
  for (int g = 0; g < 4; g++)
#pragma unroll
    for (int ks = 0; ks < 4; ks++)
      bfrag[g][ks] = *(const bf16x8*)(WhT + (size_t)(g * HH + j) * HH + ks * 32 + q * 8);

  // zero both h buffers (unowned rows stay 0 -> garbage C rows are finite)
  for (int i = tid; i < 2 * 16 * (HH + 8); i += 512) ((__bf16*)hlds)[i] = (__bf16)0.f;
  __syncthreads();
  const int d0 = done[b];
  float c = c0[(size_t)b * HH + j];
  hlds[0][row][j] = d0 ? (__bf16)0.f : (__bf16)h0[(size_t)b * HH + j];
  __syncthreads();

  const size_t tstride = (size_t)16 * 4 * 2048;   // Xg elems per timestep
  const __bf16* xpA = Xg + (size_t)(bg * 4 + R0) * 2048 + j * 16 + q * 4;
  const __bf16* xpB = xpA + tstride;
  const int* dpA = done + b;
  const int* dpB = dpA + BB;

  // startup: wait for producers of t=0,1 before first Xg loads
  { int f = ld_flag(flags + FLAG(0));
    while (f < 2) { __builtin_amdgcn_s_sleep(2); f = ld_flag(flags + FLAG(0)); } }
  { int f = ld_flag(flags + FLAG(1));
    while (f < 2) { __builtin_amdgcn_s_sleep(2); f = ld_flag(flags + FLAG(1)); } }
  uint2 xgA = ld_xg8(xpA);  xpA += 2 * tstride;
  uint2 xgB = ld_xg8(xpB);  xpB += 2 * tstride;
  int dnA = *dpA; dpA += 2 * BB;
  int dnB = *dpB; dpB += 2 * BB;
  // flag prefetch pipeline, 2 steps ahead of the data prefetch
  int fA = ld_flag(flags + FLAG(2));
  int fB = ld_flag(flags + FLAG(3));

  float* op = out + (size_t)b * HH + j;
  float nh = 0.f;

#define SCAN_STEP(XGC, DNC, DNW, RD, WR)                                      \
  {                                                                           \
    bf16x8 af[4];                                                             \
    _Pragma("unroll")                                                         \
    for (int ks = 0; ks < 4; ks++)                                            \
      af[ks] = *(const bf16x8*)&hlds[RD][l15][ks * 32 + q * 8];               \
    union { uint2 u; __bf16 h[4]; } ux; ux.u = (XGC);                         \
    float gv[4];                                                              \
    _Pragma("unroll")                                                         \
    for (int g = 0; g < 4; g++) {                                             \
      float xv = (float)ux.h[g];                                              \
      f32x4 accA = {xv, xv, xv, xv};                                          \
      accA = __builtin_amdgcn_mfma_f32_16x16x32_bf16(af[0], bfrag[g][0], accA, 0, 0, 0); \
      accA = __builtin_amdgcn_mfma_f32_16x16x32_bf16(af[2], bfrag[g][2], accA, 0, 0, 0); \
      f32x4 accB = {0.f, 0.f, 0.f, 0.f};                                      \
      accB = __builtin_amdgcn_mfma_f32_16x16x32_bf16(af[1], bfrag[g][1], accB, 0, 0, 0); \
      accB = __builtin_amdgcn_mfma_f32_16x16x32_bf16(af[3], bfrag[g][3], accB, 0, 0, 0); \
      gv[g] = accA[R0] + accB[R0];                                            \
    }                                                                         \
    float cprev = (DNC) ? 0.f : c;                                            \
    float nc = __builtin_fmaf(fast_sig(gv[1]), cprev, fast_sig(gv[0]) * fast_tanh(gv[2])); \
    nh = fast_sig(gv[3]) * fast_tanh(nc);                                     \
    c = nc;                                                                   \
    hlds[WR][row][j] = (DNW) ? (__bf16)0.f : (__bf16)nh;                      \
    *op = nh; op += BB * HH;                                                  \
    lgkm_barrier();                                                           \
  }

  for (int t = 0; t < TT; t += 2) {
    // ---- step t (read hlds[0], write hlds[1], h-mask = done[t+1] = dnB) ----
    {
      uint2 xg_c = xgA; int dn_c = dnA, dn_w = dnB;
      if (t + 2 < TT) {
        while (fA < 2) { __builtin_amdgcn_s_sleep(1); fA = ld_flag(flags + FLAG(t + 2)); }
        xgA = ld_xg8(xpA); dnA = *dpA;
        fA = (t + 4 < TT) ? ld_flag(flags + FLAG(t + 4)) : 2;
      }
      xpA += 2 * tstride; dpA += 2 * BB;
      SCAN_STEP(xg_c, dn_c, dn_w, 0, 1)
    }
    // ---- step t+1 (read hlds[1], write hlds[0], h-mask = done[t+2] = dnA) --
    {
      uint2 xg_c = xgB; int dn_c = dnB, dn_w = dnA;
      if (t + 3 < TT) {
        while (fB < 2) { __builtin_amdgcn_s_sleep(1); fB = ld_flag(flags + FLAG(t + 3)); }
        xgB = ld_xg8(xpB); dnB = *dpB;
        fB = (t + 5 < TT) ? ld_flag(flags + FLAG(t + 5)) : 2;
      }
      xpB += 2 * tstride; dpB += 2 * BB;
      SCAN_STEP(xg_c, dn_c, dn_w, 1, 0)
    }
  }
#undef SCAN_STEP

  float* cT = out + (size_t)TT * BB * HH;
  float* hT = cT + (size_t)BB * HH;
  cT[(size_t)b * HH + j] = c;
  hT[(size_t)b * HH + j] = nh;
}

// ---------------- fused producer/consumer kernel ---------------------------
// Grid = 256 blocks (~1 per CU). Blocks 0..63: scan (consumers, poll flags).
// Blocks 64..255: 192 persistent gemm producers, ~5.3 tiles each.
// Producers never wait on consumers -> forward progress under any placement;
// worst case degenerates to serial.
__global__ __launch_bounds__(512, 2)
void fused_kernel(const float* __restrict__ obs, const __bf16* __restrict__ WiT,
                  const float* __restrict__ bias, __bf16* __restrict__ Xg,
                  const __bf16* __restrict__ WhT, const int* __restrict__ done,
                  const float* __restrict__ c0, const float* __restrict__ h0,
                  float* __restrict__ out, int* __restrict__ flags) {
  __shared__ __align__(16) char smem[32768];   // gemm eld 32KB / Alds 10KB / scan 8.7KB
  if (blockIdx.x < 64) {
    __bf16 (*hlds)[16][HH + 8] = (__bf16 (*)[16][HH + 8])smem;
    const int bg = blockIdx.x >> 2;
    switch (blockIdx.x & 3) {
      case 0: scan_body<0>(Xg, WhT, done, c0, h0, out, flags, bg, hlds); break;
      case 1: scan_body<1>(Xg, WhT, done, c0, h0, out, flags, bg, hlds); break;
      case 2: scan_body<2>(Xg, WhT, done, c0, h0, out, flags, bg, hlds); break;
      case 3: scan_body<3>(Xg, WhT, done, c0, h0, out, flags, bg, hlds); break;
    }
  } else {
    gemm_body(obs, WiT, bias, Xg, flags, blockIdx.x - 64, (__bf16*)smem);
  }
}

// ---------------- launch ----------------
extern "C" void kernel_launch(void* const* d_in, const int* in_sizes, int n_in,
                              void* d_out, int out_size, void* d_ws, size_t ws_size,
                              hipStream_t stream) {
  const float* c0   = (const float*)d_in[0];
  const float* h0   = (const float*)d_in[1];
  const float* obs  = (const float*)d_in[2];
  const int*   done = (const int*)d_in[3];
  const float* Wi   = (const float*)d_in[4];
  const float* Wh   = (const float*)d_in[5];
  const float* bias = (const float*)d_in[6];
  float* out = (float*)d_out;

  char* ws = (char*)d_ws;
  // ws layout: Xg bf16 128 MiB; WiT 512 KiB; WhT 128 KiB; flags 32 KiB
  __bf16* Xg  = (__bf16*)ws;
  __bf16* WiT = (__bf16*)(ws + (size_t)134217728);
  __bf16* WhT = (__bf16*)(ws + (size_t)134217728 + 524288);
  int*  flags = (int*)(ws + (size_t)134217728 + 524288 + 131072);

  wconv_kernel<<<dim3(1024), dim3(256), 0, stream>>>(Wi, Wh, WiT, WhT, flags);
  fused_kernel<<<dim3(256), dim3(512), 0, stream>>>(obs, WiT, bias, Xg, WhT, done,
                                                    c0, h0, out, flags);
}

// Round 6
// 745.199 us; speedup vs baseline: 1.0435x; 1.0435x over previous
//
#include <hip/hip_runtime.h>
#include <hip/hip_bf16.h>
#include <cstdint>
#include <cstddef>

// Problem constants
#define TT  512
#define BB  256
#define DIN 512
#define HH  128
#define NG  512   // 4*H

typedef __bf16 bf16x8 __attribute__((ext_vector_type(8)));
typedef float  f32x4  __attribute__((ext_vector_type(4)));

// ---- nonlinearities: 1 exp2 + 1 rcp each, branch-free --------------------
__device__ __forceinline__ float fast_sig(float x) {
  float e = __builtin_amdgcn_exp2f(-1.44269504f * x);
  return __builtin_amdgcn_rcpf(1.f + e);
}
__device__ __forceinline__ float fast_tanh(float x) {
  float e = __builtin_amdgcn_exp2f(-2.88539008f * x);
  return __builtin_fmaf(2.f, __builtin_amdgcn_rcpf(1.f + e), -1.f);
}

// LDS-visibility-only barrier: vmcnt (global loads/stores) stays in flight.
__device__ __forceinline__ void lgkm_barrier() {
  asm volatile("s_waitcnt lgkmcnt(0)\n\ts_barrier" ::: "memory");
}

// Producer->consumer handoff, NO buffer_wbl2 anywhere:
//  - producer data stores are sc1 (agent-scope write-through, bypass L2) in
//    unit-stride 512B-per-wave-instruction runs (full-line coverage -> no
//    partial-sector penalty; this was R2's confound, fixed by the LDS
//    transpose epilogue);
//  - __syncthreads() drains each wave's vmcnt -> all sc1 stores are at L3
//    (the coherence point) before the RELAXED flag add issues;
//  - consumers read Xg/flags with sc1 loads (bypass their possibly-stale
//    local L2; Xg addresses are re-written every harness iteration).
__device__ __forceinline__ int ld_flag(const int* p) {
  return __hip_atomic_load(p, __ATOMIC_RELAXED, __HIP_MEMORY_SCOPE_AGENT);
}
__device__ __forceinline__ uint2 ld_xg8(const __bf16* p) {
  unsigned long long v = __hip_atomic_load((const unsigned long long*)p,
                                           __ATOMIC_RELAXED, __HIP_MEMORY_SCOPE_AGENT);
  union { unsigned long long u; uint2 v2; } cv; cv.u = v;
  return cv.v2;
}
__device__ __forceinline__ void st_xg8(unsigned long long* p, unsigned long long v) {
  __hip_atomic_store(p, v, __ATOMIC_RELAXED, __HIP_MEMORY_SCOPE_AGENT);
}

// flags padded to one 64B line per timestep (16 ints): 512 consumer waves
// polling t+2..t+5 never contend with the producer's RMW on flags[t].
#define FLAG(t) ((t) * 16)

// ---------------- P0: weight transpose + fp32->bf16 convert + flag reset ---
__global__ void wconv_kernel(const float* __restrict__ Wi, const float* __restrict__ Wh,
                             __bf16* __restrict__ WiT, __bf16* __restrict__ WhT,
                             int* __restrict__ flags) {
  int idx = blockIdx.x * 256 + threadIdx.x;
  if (idx < TT * 16) flags[idx] = 0;           // 512 lines x 16 ints
  if (idx < DIN * NG) {
    int n = idx >> 9, k = idx & 511;
    WiT[(size_t)n * DIN + k] = (__bf16)Wi[(size_t)k * NG + n];
  }
  if (idx < HH * NG) {
    int n = idx >> 7, k = idx & 127;
    WhT[(size_t)n * HH + k] = (__bf16)Wh[(size_t)k * NG + n];
  }
}

// ---------------- gemm body: Xg = obs @ Wi + b (persistent producer) -------
// R4's LDS-staged, distance-2-prefetch main loop. Epilogue: stage each
// mt-pair's C-subtile through a 32KB LDS transpose buffer (consumer layout),
// then stream it out as unit-stride sc1 write-through stores (8B/lane,
// 512B/wave-instr, full line coverage). No L2 dirty state -> no wbl2 walk
// is ever needed to publish; the flag add is RELAXED.
__device__ __forceinline__ void gemm_body(
    const float* __restrict__ obs, const __bf16* __restrict__ WiT,
    const float* __restrict__ bias, __bf16* __restrict__ Xg,
    int* __restrict__ flags, int p, __bf16* smem_) {
  __bf16 (*Alds)[40] = (__bf16 (*)[40])smem_;   // 10240 B (main loop)
  __bf16* eld = smem_;                          // 32768 B (epilogue, aliased)
  const int tid  = threadIdx.x;
  const int wave = tid >> 6, lane = tid & 63;
  const int l15  = lane & 15, q = lane >> 4;
  const int am = tid >> 2, aq = tid & 3;
  const int g_out = wave >> 1;                  // epilogue gate index

  const __bf16* bptr[4];
  float bbv[4];
#pragma unroll
  for (int nt = 0; nt < 4; nt++) {
    bptr[nt] = WiT + (size_t)(wave * 64 + nt * 16 + l15) * DIN + q * 8;
    bbv[nt]  = bias[wave * 64 + nt * 16 + l15];
  }

  for (int bid = p; bid < 2 * TT; bid += 192) {
    const size_t m0 = (size_t)bid * 128;

    const f32x4 fzero = {0.f, 0.f, 0.f, 0.f};
    f32x4 acc[8][4];
#pragma unroll
    for (int i = 0; i < 8; i++)
#pragma unroll
      for (int jj = 0; jj < 4; jj++) acc[i][jj] = fzero;

    const float* aptr = obs + (m0 + am) * DIN + aq * 8;

    // distance-2 slots
    float4 a0[2], a1[2];
    bf16x8 bs[2][4];
    a0[0] = *(const float4*)(aptr);      a1[0] = *(const float4*)(aptr + 4);
    a0[1] = *(const float4*)(aptr + 32); a1[1] = *(const float4*)(aptr + 36);
#pragma unroll
    for (int nt = 0; nt < 4; nt++) {
      bs[0][nt] = *(const bf16x8*)(bptr[nt]);
      bs[1][nt] = *(const bf16x8*)(bptr[nt] + 32);
    }

#pragma unroll
    for (int kc = 0; kc < DIN; kc += 32) {
      const int sl = (kc >> 5) & 1;
      if (kc) lgkm_barrier();            // prev frag reads drained
      { // stage A tile (consumes A slot sl)
        float4 f0 = a0[sl], f1 = a1[sl];
        bf16x8 v = {(__bf16)f0.x, (__bf16)f0.y, (__bf16)f0.z, (__bf16)f0.w,
                    (__bf16)f1.x, (__bf16)f1.y, (__bf16)f1.z, (__bf16)f1.w};
        *(bf16x8*)&Alds[am][aq * 8] = v;
      }
      lgkm_barrier();                    // A visible; vmcnt untouched
      int kp = kc + 64; if (kp > DIN - 32) kp = DIN - 32;   // clamped tail (unused)
      a0[sl] = *(const float4*)(aptr + kp);
      a1[sl] = *(const float4*)(aptr + kp + 4);
#pragma unroll
      for (int mt = 0; mt < 8; mt++) {
        bf16x8 af = *(const bf16x8*)&Alds[mt * 16 + l15][q * 8];
#pragma unroll
        for (int nt = 0; nt < 4; nt++)
          acc[mt][nt] = __builtin_amdgcn_mfma_f32_16x16x32_bf16(af, bs[sl][nt], acc[mt][nt], 0, 0, 0);
      }
#pragma unroll
      for (int nt = 0; nt < 4; nt++)     // refill B slot for kc+64
        bs[sl][nt] = *(const bf16x8*)(bptr[nt] + kp);
    }

    // ---- epilogue: LDS-transpose to consumer layout, sc1 coalesced out ----
    // C row = mt*16 + q*4 + r; b = half*128 + row -> bg = half*8+mt, r0 = r.
    // Consumer layout within a tile: [mt][r][jj][q][g], jj=(wave&1)*64+nt*16
    // +l15, g=wave>>1. Two mt's (32KB) staged per pass, 4 passes.
    const int t = bid >> 1;
    const int half = bid & 1;
#pragma unroll 1
    for (int mtp = 0; mtp < 4; mtp++) {
      __syncthreads();                   // buffer free (Alds or prev pass)
#pragma unroll
      for (int mh = 0; mh < 2; mh++) {
        const int mt = mtp * 2 + mh;
#pragma unroll
        for (int nt = 0; nt < 4; nt++) {
          const int jj = (wave & 1) * 64 + nt * 16 + l15;
          const float bb = bbv[nt];
#pragma unroll
          for (int r = 0; r < 4; r++)
            eld[mh * 8192 + r * 2048 + jj * 16 + q * 4 + g_out] =
                (__bf16)(acc[mt][nt][r] + bb);
        }
      }
      __syncthreads();                   // staged
      unsigned long long* dst =
          (unsigned long long*)(Xg + (size_t)(t * 16 + half * 8 + mtp * 2) * 8192);
      const unsigned long long* src = (const unsigned long long*)eld;
#pragma unroll
      for (int u = 0; u < 8; u++)        // 32KB = 8 x (512 thr x 8B), unit-stride
        st_xg8(dst + u * 512 + tid, src[u * 512 + tid]);
    }

    // __syncthreads drains each wave's vmcnt -> all sc1 stores are at L3
    // before the RELAXED flag add issues. No wbl2, no L2 disruption.
    __syncthreads();
    if (tid == 0)
      __hip_atomic_fetch_add(flags + FLAG(t), 1, __ATOMIC_RELAXED, __HIP_MEMORY_SCOPE_AGENT);
  }
}

// ---------------- scan body (consumer) -------------------------------------
template<int R0>
__device__ __forceinline__ void scan_body(
    const __bf16* __restrict__ Xg, const __bf16* __restrict__ WhT,
    const int* __restrict__ done, const float* __restrict__ c0,
    const float* __restrict__ h0, float* __restrict__ out,
    const int* __restrict__ flags,
    int bg, __bf16 (*hlds)[16][HH + 8]) {
  const int tid  = threadIdx.x;
  const int wave = tid >> 6, lane = tid & 63;
  const int l15  = lane & 15, q = lane >> 4;
  const int b0 = bg * 16;
  const int j  = wave * 16 + l15;
  const int b  = b0 + q * 4 + R0;        // owned batch row
  const int row = q * 4 + R0;            // LDS row for owned batch

  // Wh B-fragments resident in registers (64 VGPR/lane)
  bf16x8 bfrag[4][4];
#pragma unroll
  for (int g = 0; g < 4; g++)
#pragma unroll
    for (int ks = 0; ks < 4; ks++)
      bfrag[g][ks] = *(const bf16x8*)(WhT + (size_t)(g * HH + j) * HH + ks * 32 + q * 8);

  // zero both h buffers (unowned rows stay 0 -> garbage C rows are finite)
  for (int i = tid; i < 2 * 16 * (HH + 8); i += 512) ((__bf16*)hlds)[i] = (__bf16)0.f;
  __syncthreads();
  const int d0 = done[b];
  float c = c0[(size_t)b * HH + j];
  hlds[0][row][j] = d0 ? (__bf16)0.f : (__bf16)h0[(size_t)b * HH + j];
  __syncthreads();

  const size_t tstride = (size_t)16 * 4 * 2048;   // Xg elems per timestep
  const __bf16* xpA = Xg + (size_t)(bg * 4 + R0) * 2048 + j * 16 + q * 4;
  const __bf16* xpB = xpA + tstride;
  const int* dpA = done + b;
  const int* dpB = dpA + BB;

  // startup: wait for producers of t=0,1 before first Xg loads
  { int f = ld_flag(flags + FLAG(0));
    while (f < 2) { __builtin_amdgcn_s_sleep(2); f = ld_flag(flags + FLAG(0)); } }
  { int f = ld_flag(flags + FLAG(1));
    while (f < 2) { __builtin_amdgcn_s_sleep(2); f = ld_flag(flags + FLAG(1)); } }
  uint2 xgA = ld_xg8(xpA);  xpA += 2 * tstride;
  uint2 xgB = ld_xg8(xpB);  xpB += 2 * tstride;
  int dnA = *dpA; dpA += 2 * BB;
  int dnB = *dpB; dpB += 2 * BB;
  // flag prefetch pipeline, 2 steps ahead of the data prefetch
  int fA = ld_flag(flags + FLAG(2));
  int fB = ld_flag(flags + FLAG(3));

  float* op = out + (size_t)b * HH + j;
  float nh = 0.f;

#define SCAN_STEP(XGC, DNC, DNW, RD, WR)                                      \
  {                                                                           \
    bf16x8 af[4];                                                             \
    _Pragma("unroll")                                                         \
    for (int ks = 0; ks < 4; ks++)                                            \
      af[ks] = *(const bf16x8*)&hlds[RD][l15][ks * 32 + q * 8];               \
    union { uint2 u; __bf16 h[4]; } ux; ux.u = (XGC);                         \
    float gv[4];                                                              \
    _Pragma("unroll")                                                         \
    for (int g = 0; g < 4; g++) {                                             \
      float xv = (float)ux.h[g];                                              \
      f32x4 accA = {xv, xv, xv, xv};                                          \
      accA = __builtin_amdgcn_mfma_f32_16x16x32_bf16(af[0], bfrag[g][0], accA, 0, 0, 0); \
      accA = __builtin_amdgcn_mfma_f32_16x16x32_bf16(af[2], bfrag[g][2], accA, 0, 0, 0); \
      f32x4 accB = {0.f, 0.f, 0.f, 0.f};                                      \
      accB = __builtin_amdgcn_mfma_f32_16x16x32_bf16(af[1], bfrag[g][1], accB, 0, 0, 0); \
      accB = __builtin_amdgcn_mfma_f32_16x16x32_bf16(af[3], bfrag[g][3], accB, 0, 0, 0); \
      gv[g] = accA[R0] + accB[R0];                                            \
    }                                                                         \
    float cprev = (DNC) ? 0.f : c;                                            \
    float nc = __builtin_fmaf(fast_sig(gv[1]), cprev, fast_sig(gv[0]) * fast_tanh(gv[2])); \
    nh = fast_sig(gv[3]) * fast_tanh(nc);                                     \
    c = nc;                                                                   \
    hlds[WR][row][j] = (DNW) ? (__bf16)0.f : (__bf16)nh;                      \
    *op = nh; op += BB * HH;                                                  \
    lgkm_barrier();                                                           \
  }

  for (int t = 0; t < TT; t += 2) {
    // ---- step t (read hlds[0], write hlds[1], h-mask = done[t+1] = dnB) ----
    {
      uint2 xg_c = xgA; int dn_c = dnA, dn_w = dnB;
      if (t + 2 < TT) {
        while (fA < 2) { __builtin_amdgcn_s_sleep(1); fA = ld_flag(flags + FLAG(t + 2)); }
        xgA = ld_xg8(xpA); dnA = *dpA;
        fA = (t + 4 < TT) ? ld_flag(flags + FLAG(t + 4)) : 2;
      }
      xpA += 2 * tstride; dpA += 2 * BB;
      SCAN_STEP(xg_c, dn_c, dn_w, 0, 1)
    }
    // ---- step t+1 (read hlds[1], write hlds[0], h-mask = done[t+2] = dnA) --
    {
      uint2 xg_c = xgB; int dn_c = dnB, dn_w = dnA;
      if (t + 3 < TT) {
        while (fB < 2) { __builtin_amdgcn_s_sleep(1); fB = ld_flag(flags + FLAG(t + 3)); }
        xgB = ld_xg8(xpB); dnB = *dpB;
        fB = (t + 5 < TT) ? ld_flag(flags + FLAG(t + 5)) : 2;
      }
      xpB += 2 * tstride; dpB += 2 * BB;
      SCAN_STEP(xg_c, dn_c, dn_w, 1, 0)
    }
  }
#undef SCAN_STEP

  float* cT = out + (size_t)TT * BB * HH;
  float* hT = cT + (size_t)BB * HH;
  cT[(size_t)b * HH + j] = c;
  hT[(size_t)b * HH + j] = nh;
}

// ---------------- fused producer/consumer kernel ---------------------------
// Grid = 256 blocks (~1 per CU). Blocks 0..63: scan (consumers, poll flags).
// Blocks 64..255: 192 persistent gemm producers, ~5.3 tiles each.
// Producers never wait on consumers -> forward progress under any placement;
// worst case degenerates to serial.
__global__ __launch_bounds__(512, 2)
void fused_kernel(const float* __restrict__ obs, const __bf16* __restrict__ WiT,
                  const float* __restrict__ bias, __bf16* __restrict__ Xg,
                  const __bf16* __restrict__ WhT, const int* __restrict__ done,
                  const float* __restrict__ c0, const float* __restrict__ h0,
                  float* __restrict__ out, int* __restrict__ flags) {
  __shared__ __align__(16) char smem[32768];   // gemm eld 32KB / Alds 10KB / scan 8.7KB
  if (blockIdx.x < 64) {
    __bf16 (*hlds)[16][HH + 8] = (__bf16 (*)[16][HH + 8])smem;
    const int bg = blockIdx.x >> 2;
    switch (blockIdx.x & 3) {
      case 0: scan_body<0>(Xg, WhT, done, c0, h0, out, flags, bg, hlds); break;
      case 1: scan_body<1>(Xg, WhT, done, c0, h0, out, flags, bg, hlds); break;
      case 2: scan_body<2>(Xg, WhT, done, c0, h0, out, flags, bg, hlds); break;
      case 3: scan_body<3>(Xg, WhT, done, c0, h0, out, flags, bg, hlds); break;
    }
  } else {
    gemm_body(obs, WiT, bias, Xg, flags, blockIdx.x - 64, (__bf16*)smem);
  }
}

// ---------------- launch ----------------
extern "C" void kernel_launch(void* const* d_in, const int* in_sizes, int n_in,
                              void* d_out, int out_size, void* d_ws, size_t ws_size,
                              hipStream_t stream) {
  const float* c0   = (const float*)d_in[0];
  const float* h0   = (const float*)d_in[1];
  const float* obs  = (const float*)d_in[2];
  const int*   done = (const int*)d_in[3];
  const float* Wi   = (const float*)d_in[4];
  const float* Wh   = (const float*)d_in[5];
  const float* bias = (const float*)d_in[6];
  float* out = (float*)d_out;

  char* ws = (char*)d_ws;
  // ws layout: Xg bf16 128 MiB; WiT 512 KiB; WhT 128 KiB; flags 32 KiB
  __bf16* Xg  = (__bf16*)ws;
  __bf16* WiT = (__bf16*)(ws + (size_t)134217728);
  __bf16* WhT = (__bf16*)(ws + (size_t)134217728 + 524288);
  int*  flags = (int*)(ws + (size_t)134217728 + 524288 + 131072);

  wconv_kernel<<<dim3(1024), dim3(256), 0, stream>>>(Wi, Wh, WiT, WhT, flags);
  fused_kernel<<<dim3(256), dim3(512), 0, stream>>>(obs, WiT, bias, Xg, WhT, done,
                                                    c0, h0, out, flags);
}